// Round 8
// baseline (797.167 us; speedup 1.0000x reference)
//
#include <hip/hip_runtime.h>

// 2-layer LSTM (H=50) + FC head. Transposed-MFMA fp16, cross-layer pipelined,
// VALU-diet, 2-blocks-per-CU edition.
//  - gates^T = W @ h^T; A = weights (register-resident frags), B = h (LDS).
//  - Gate rows permuted p = 4*j + g: one lane owns all 4 gates of unit
//    j = w*4 + qq, batch l15 -> cell update fully in-register.
//  - Phase p computes L1[p] and L2[p-1]; ONE barrier/phase, 513 phases.
//  - x-term and ALL biases ride the MFMA's dead K-lanes (h1 k=50 = x[t],
//    k=51 = 1.0; L1 A-frag k=50/51 = w_ih0/biasL1; w_ih1 A-frag k=51 = biasL2).
//  - Activations division-free: v_rcp + v_exp2 builtins.
//  - NB=8, grid=512 -> 2 independent blocks per CU (26 waves) so one block's
//    barrier drain is hidden by the other block's issue. MFMA columns 8..15
//    carry garbage; columns are independent in MFMA, so it never leaks.
// B=4096, T=512. 832 threads (13 waves = 13 p-tiles).

#define HID 50
#define SEQ 512
#define NB 8
#define NTHREADS 832
#define XP 516            // xs row stride (floats)

typedef _Float16 f16x8 __attribute__((ext_vector_type(8)));
typedef float    f32x4 __attribute__((ext_vector_type(4)));

#define LOG2E 1.44269504f

__device__ __forceinline__ float sigf(float x) {
    return __builtin_amdgcn_rcpf(1.0f + __builtin_amdgcn_exp2f(x * -LOG2E));
}
__device__ __forceinline__ float tanh_fast(float x) {
    return 1.0f - 2.0f * __builtin_amdgcn_rcpf(
        1.0f + __builtin_amdgcn_exp2f(x * (2.0f * LOG2E)));
}
__device__ __forceinline__ float lstm_cell(const f32x4 g, float& c) {
    const float ii = sigf(g[0]);
    const float ff = sigf(g[1]);
    const float gg = tanh_fast(g[2]);
    const float oo = sigf(g[3]);
    c = ff * c + ii * gg;
    return oo * tanh_fast(c);
}

// h LDS layout: 16B chunk (kt*4+qh)*16 + m holds h[m][k = kt*32+qh*8+0..7].
// B-frag reader (lane m=l15, quad qq, k-chunk kt) reads chunk (kt*4+qq)*16+m:
// 64 lanes -> 64 distinct contiguous chunks, conflict-free ds_read_b128.
// Writer of h[m][j]: chunk ((j>>5)*4+((j>>3)&3))*16 + m, half j&7.

__global__ __launch_bounds__(NTHREADS, 1)
void lstm2_fc_2cu(const float* __restrict__ x,
                  const float* __restrict__ w_ih0,
                  const float* __restrict__ w_hh0,
                  const float* __restrict__ b_ih0,
                  const float* __restrict__ b_hh0,
                  const float* __restrict__ w_ih1,
                  const float* __restrict__ w_hh1,
                  const float* __restrict__ b_ih1,
                  const float* __restrict__ b_hh1,
                  const float* __restrict__ fc_w,
                  const float* __restrict__ fc_b,
                  float* __restrict__ out)
{
    __shared__ float xs[NB * XP];        // 16.5 KB  x for all 512 steps
    __shared__ f16x8 h1f[2][128];        //  4 KB    h1 double-buffered, frag layout
    __shared__ f16x8 h2f[2][128];        //  4 KB    h2 double-buffered

    const int tid = threadIdx.x;
    const int b0  = blockIdx.x * NB;
    const int w   = tid >> 6;            // wave id 0..12 == p-tile id
    const int l15 = tid & 15;            // MFMA lane column (batch m)
    const int qq  = (tid >> 4) & 3;      // MFMA lane quad
    const int l7  = l15 & 7;             // clamped batch for x reads (m>=8 dup)

    // ---- stage x into LDS (coalesced float4) ----
    for (int idx = tid; idx < NB * 128; idx += NTHREADS) {
        const int b  = idx >> 7;
        const int t4 = idx & 127;
        *(float4*)&xs[b * XP + t4 * 4] =
            *(const float4*)&x[(size_t)(b0 + b) * SEQ + t4 * 4];
    }
    // zero the x[512..515] pad column (read at the last x-prefetch)
    if (tid < NB) {
        const float4 z = {0.f, 0.f, 0.f, 0.f};
        *(float4*)&xs[tid * XP + 512] = z;
    }
    // ---- zero h buffers ----
    if (tid < 256) {
        f16x8 z = {};
        h1f[tid >> 7][tid & 127] = z;
        h2f[tid >> 7][tid & 127] = z;
    }

    // ---- load weight A-fragments (one-time), gate rows permuted ----
    // A-frag: lane holds W[p = w*16 + l15][k = kt*32 + qq*8 + j], source gate
    // row n(p) = (p&3)*HID + (p>>2). Specials: mat0 k=50 -> w_ih0, k=51 ->
    // biasL1; mat1 k=51 -> biasL2. Zero elsewhere outside k<50 / p<200.
    const float* mats[3] = { w_hh0, w_ih1, w_hh1 };
    f16x8 wa[3][2];                      // [mat][kt] = 6 frags = 24 VGPR
    {
        const int  pA  = w * 16 + l15;
        const bool pok = (pA < 4 * HID);
        const int  n   = pok ? ((pA & 3) * HID + (pA >> 2)) : 0;
#pragma unroll
        for (int mi = 0; mi < 3; ++mi) {
#pragma unroll
            for (int kt = 0; kt < 2; ++kt) {
                f16x8 f;
#pragma unroll
                for (int j = 0; j < 8; ++j) {
                    const int k = kt * 32 + qq * 8 + j;
                    float v = 0.0f;
                    if (pok) {
                        if (k < HID)                     v = mats[mi][n * HID + k];
                        else if (mi == 0 && k == HID)    v = w_ih0[n];
                        else if (mi == 0 && k == HID+1)  v = b_ih0[n] + b_hh0[n];
                        else if (mi == 1 && k == HID+1)  v = b_ih1[n] + b_hh1[n];
                    }
                    f[j] = (_Float16)v;
                }
                wa[mi][kt] = f;
            }
        }
    }

    // ---- h-write offset: this lane owns unit j = w*4 + qq, batch l15 ----
    const int ju   = w * 4 + qq;                       // <= 51
    const int wOff = ((((ju >> 5) * 4) + ((ju >> 3) & 3)) * 16 + l15) * 8 + (ju & 7);
    const bool isXlane = (ju == HID);                  // writes x into h1 k=50
    const bool isOne   = (ju == HID + 1);              // writes 1.0 into k=51

    float c1 = 0.f, c2 = 0.f;
    int cur = 0;

    __syncthreads();   // xs + zeros visible

    // ---- seed h1f[0] specials: k=50 = x[m][0], k=51 = 1.0 ----
    if (tid < 16) {
        _Float16* e0 = (_Float16*)&h1f[0][96 + tid];
        e0[2] = (_Float16)x[(size_t)(b0 + (tid & 7)) * SEQ];
        e0[3] = (_Float16)1.0f;
    }
    __syncthreads();

    // ---- 513 phases: phase p = L1 step p  +  L2 step p-1 ----
#pragma unroll 2
    for (int p = 0; p <= SEQ; ++p) {
        const f16x8* h1o = h1f[cur];         // h1[p-1] (+ x[p], 1.0 in k=50/51)
        const f16x8* h2o = h2f[cur];         // h2[p-2]
        f16x8* h1n = h1f[cur ^ 1];           // h1[p]
        f16x8* h2n = h2f[cur ^ 1];           // h2[p-1]

        const f16x8 hb0 = h1o[qq * 16 + l15];        // shared by L1 and L2
        const f16x8 hb1 = h1o[64 + qq * 16 + l15];

        if (p < SEQ) {
            // L1 step p: gates = W_hh0 @ h1[p-1] + w_ih0*x[p] + biasL1 (in MFMA)
            f32x4 acc = {0.f, 0.f, 0.f, 0.f};
            acc = __builtin_amdgcn_mfma_f32_16x16x32_f16(wa[0][0], hb0, acc, 0, 0, 0);
            acc = __builtin_amdgcn_mfma_f32_16x16x32_f16(wa[0][1], hb1, acc, 0, 0, 0);
            _Float16 hw = (_Float16)lstm_cell(acc, c1);
            if (isXlane) hw = (_Float16)xs[l7 * XP + (p + 1)];  // x for phase p+1
            if (isOne)   hw = (_Float16)1.0f;
            ((_Float16*)h1n)[wOff] = hw;
        }
        if (p > 0) {
            // L2 step p-1: gates = W_ih1 @ h1[p-1] + W_hh1 @ h2[p-2] + biasL2
            const f16x8 sb0 = h2o[qq * 16 + l15];
            const f16x8 sb1 = h2o[64 + qq * 16 + l15];
            f32x4 acc = {0.f, 0.f, 0.f, 0.f};
            acc = __builtin_amdgcn_mfma_f32_16x16x32_f16(wa[1][0], hb0, acc, 0, 0, 0);
            acc = __builtin_amdgcn_mfma_f32_16x16x32_f16(wa[1][1], hb1, acc, 0, 0, 0);
            acc = __builtin_amdgcn_mfma_f32_16x16x32_f16(wa[2][0], sb0, acc, 0, 0, 0);
            acc = __builtin_amdgcn_mfma_f32_16x16x32_f16(wa[2][1], sb1, acc, 0, 0, 0);
            ((_Float16*)h2n)[wOff] = (_Float16)lstm_cell(acc, c2);
        }
        __syncthreads();   // h1[p], h2[p-1] visible
        cur ^= 1;
    }
    // after 513 phases: cur = 1, h2f[cur] = h2[511]

    // ============ FC head: out[b] = h2[T-1] . fc_w + fc_b ============
    if (tid < NB) {
        const int m = tid;
        const _Float16* h2e = (const _Float16*)h2f[cur];
        float s = fc_b[0];
        for (int j = 0; j < HID; ++j) {
            const int chunk = (((j >> 5) * 4) + ((j >> 3) & 3)) * 16 + m;
            s += fc_w[j] * (float)h2e[chunk * 8 + (j & 7)];
        }
        out[b0 + m] = s;
    }
}

extern "C" void kernel_launch(void* const* d_in, const int* in_sizes, int n_in,
                              void* d_out, int out_size, void* d_ws, size_t ws_size,
                              hipStream_t stream) {
    const float* x     = (const float*)d_in[0];
    const float* w_ih0 = (const float*)d_in[1];
    const float* w_hh0 = (const float*)d_in[2];
    const float* b_ih0 = (const float*)d_in[3];
    const float* b_hh0 = (const float*)d_in[4];
    const float* w_ih1 = (const float*)d_in[5];
    const float* w_hh1 = (const float*)d_in[6];
    const float* b_ih1 = (const float*)d_in[7];
    const float* b_hh1 = (const float*)d_in[8];
    const float* fc_w  = (const float*)d_in[9];
    const float* fc_b  = (const float*)d_in[10];
    float* out = (float*)d_out;

    const int B = in_sizes[0] / SEQ;  // 4096

    lstm2_fc_2cu<<<B / NB, NTHREADS, 0, stream>>>(
        x, w_ih0, w_hh0, b_ih0, b_hh0, w_ih1, w_hh1, b_ih1, b_hh1, fc_w, fc_b, out);
}

// Round 9
// 451.617 us; speedup vs baseline: 1.7651x; 1.7651x over previous
//
#include <hip/hip_runtime.h>

// 2-layer LSTM (H=50) + FC head. Transposed-MFMA fp16, cross-layer pipelined.
// R9 = R7 structure + instruction-count surgery:
//  - phases 0 / 511 / 512 peeled -> branch-free core, manual 2-phase unroll
//    with hard-coded double-buffer pointers (addresses fold to immediates).
//  - x-special handled in a wave-uniform `if (w==12)` branch (12 of 13 waves
//    skip it via s_cbranch); the 1.0 K-lane is written ONCE pre-loop.
//  - gates^T = W @ h^T; A = weights in registers, B = h in LDS frag layout;
//    gate rows permuted p = 4j+g -> cell update fully in-register;
//    x-term + all biases ride dead K-lanes (k=50: x, k=51: 1.0 / biases).
//  - activations division-free (v_rcp + v_exp2).
// B=4096, T=512. Grid 256 x 832 threads (13 waves = 13 p-tiles), NB=16.
// NOTE (R8 lesson): per-block instruction count is batch-independent ->
// batch-splitting across blocks doubles chip work; 1 block/CU @ NB=16 is right.

#define HID 50
#define SEQ 512
#define NB 16
#define NTHREADS 832
#define XP 516            // xs row stride (floats)

typedef _Float16 f16x8 __attribute__((ext_vector_type(8)));
typedef float    f32x4 __attribute__((ext_vector_type(4)));

#define LOG2E 1.44269504f

__device__ __forceinline__ float sigf(float x) {
    return __builtin_amdgcn_rcpf(1.0f + __builtin_amdgcn_exp2f(x * -LOG2E));
}
__device__ __forceinline__ float tanh_fast(float x) {
    return 1.0f - 2.0f * __builtin_amdgcn_rcpf(
        1.0f + __builtin_amdgcn_exp2f(x * (2.0f * LOG2E)));
}
__device__ __forceinline__ float lstm_cell(const f32x4 g, float& c) {
    const float ii = sigf(g[0]);
    const float ff = sigf(g[1]);
    const float gg = tanh_fast(g[2]);
    const float oo = sigf(g[3]);
    c = ff * c + ii * gg;
    return oo * tanh_fast(c);
}

// h LDS layout: 16B chunk (kt*4+qh)*16 + m holds h[m][k = kt*32+qh*8+0..7].
// Reader (lane m=l15, quad qq, k-chunk kt) reads chunk (kt*4+qq)*16+m: 64
// distinct contiguous chunks -> conflict-light ds_read_b128.
// Writer of h[m][j]: chunk ((j>>5)*4+((j>>3)&3))*16 + m, half j&7.
// j=50 -> chunk 96+m half 2 (x rides here), j=51 -> chunk 96+m half 3 (1.0).

__global__ __launch_bounds__(NTHREADS, 1)
void lstm2_fc_v9(const float* __restrict__ x,
                 const float* __restrict__ w_ih0,
                 const float* __restrict__ w_hh0,
                 const float* __restrict__ b_ih0,
                 const float* __restrict__ b_hh0,
                 const float* __restrict__ w_ih1,
                 const float* __restrict__ w_hh1,
                 const float* __restrict__ b_ih1,
                 const float* __restrict__ b_hh1,
                 const float* __restrict__ fc_w,
                 const float* __restrict__ fc_b,
                 float* __restrict__ out)
{
    __shared__ float xs[NB * XP];        // 33 KB  x for all 512 steps
    __shared__ f16x8 h1f[2][128];        //  4 KB  h1 double-buffered, frag layout
    __shared__ f16x8 h2f[2][128];        //  4 KB  h2 double-buffered

    const int tid = threadIdx.x;
    const int b0  = blockIdx.x * NB;
    const int w   = tid >> 6;            // wave id 0..12 == p-tile id
    const int l15 = tid & 15;            // MFMA lane column (batch m)
    const int qq  = (tid >> 4) & 3;      // MFMA lane quad

    // ---- stage x into LDS (coalesced float4) ----
    for (int idx = tid; idx < NB * 128; idx += NTHREADS) {
        const int b  = idx >> 7;
        const int t4 = idx & 127;
        *(float4*)&xs[b * XP + t4 * 4] =
            *(const float4*)&x[(size_t)(b0 + b) * SEQ + t4 * 4];
    }
    if (tid < NB) {                       // zero x pad column t=512..515
        const float4 z = {0.f, 0.f, 0.f, 0.f};
        *(float4*)&xs[tid * XP + 512] = z;
    }
    // ---- zero h buffers ----
    if (tid < 256) {
        f16x8 z = {};
        h1f[tid >> 7][tid & 127] = z;
        h2f[tid >> 7][tid & 127] = z;
    }

    // ---- load weight A-fragments (one-time), gate rows permuted ----
    // lane holds W[p = w*16 + l15][k = kt*32 + qq*8 + j], n(p) = (p&3)*HID+(p>>2)
    // specials: mat0 k=50 -> w_ih0, k=51 -> biasL1; mat1 k=51 -> biasL2.
    const float* mats[3] = { w_hh0, w_ih1, w_hh1 };
    f16x8 wa[3][2];                      // [mat][kt] = 6 frags = 24 VGPR
    {
        const int  pA  = w * 16 + l15;
        const bool pok = (pA < 4 * HID);
        const int  n   = pok ? ((pA & 3) * HID + (pA >> 2)) : 0;
#pragma unroll
        for (int mi = 0; mi < 3; ++mi) {
#pragma unroll
            for (int kt = 0; kt < 2; ++kt) {
                f16x8 f;
#pragma unroll
                for (int j = 0; j < 8; ++j) {
                    const int k = kt * 32 + qq * 8 + j;
                    float v = 0.0f;
                    if (pok) {
                        if (k < HID)                     v = mats[mi][n * HID + k];
                        else if (mi == 0 && k == HID)    v = w_ih0[n];
                        else if (mi == 0 && k == HID+1)  v = b_ih0[n] + b_hh0[n];
                        else if (mi == 1 && k == HID+1)  v = b_ih1[n] + b_hh1[n];
                    }
                    f[j] = (_Float16)v;
                }
                wa[mi][kt] = f;
            }
        }
    }

    // ---- per-lane invariants ----
    const int ju   = w * 4 + qq;                       // unit this lane owns (<=51)
    const int wOff = ((((ju >> 5) * 4) + ((ju >> 3) & 3)) * 16 + l15) * 8 + (ju & 7);
    const int rdo  = qq * 16 + l15;                    // B-frag chunk index, kt=0
    const float* xrow = xs + l15 * XP;                 // x row for the x-lane

    float c1 = 0.f, c2 = 0.f;

    __syncthreads();   // xs + zeros visible

    // ---- seed specials: h1f[0] k=50 = x[m][0]; k=51 = 1.0 in BOTH buffers.
    // The 1.0 lane (ju=51) never writes in-loop, so both stay valid forever.
    if (tid < NB) {
        _Float16* e0 = (_Float16*)&h1f[0][96 + tid];
        e0[2] = (_Float16)xs[tid * XP];
        e0[3] = (_Float16)1.0f;
        ((_Float16*)&h1f[1][96 + tid])[3] = (_Float16)1.0f;
    }
    __syncthreads();

    // ---- phase body: L1[p] (if doL1) + L2[p-1] (if doL2), one barrier ----
    auto phase = [&](const f16x8* __restrict__ h1o, const f16x8* __restrict__ h2o,
                     f16x8* __restrict__ h1n, f16x8* __restrict__ h2n,
                     int p, bool doL1, bool doL2) {
        const f16x8 hb0 = h1o[rdo];
        const f16x8 hb1 = h1o[64 + rdo];
        _Float16 hw1, hw2;
        if (doL1) {
            f32x4 acc = {0.f, 0.f, 0.f, 0.f};
            acc = __builtin_amdgcn_mfma_f32_16x16x32_f16(wa[0][0], hb0, acc, 0, 0, 0);
            acc = __builtin_amdgcn_mfma_f32_16x16x32_f16(wa[0][1], hb1, acc, 0, 0, 0);
            hw1 = (_Float16)lstm_cell(acc, c1);
        }
        if (doL2) {
            const f16x8 sb0 = h2o[rdo];
            const f16x8 sb1 = h2o[64 + rdo];
            f32x4 acc = {0.f, 0.f, 0.f, 0.f};
            acc = __builtin_amdgcn_mfma_f32_16x16x32_f16(wa[1][0], hb0, acc, 0, 0, 0);
            acc = __builtin_amdgcn_mfma_f32_16x16x32_f16(wa[1][1], hb1, acc, 0, 0, 0);
            acc = __builtin_amdgcn_mfma_f32_16x16x32_f16(wa[2][0], sb0, acc, 0, 0, 0);
            acc = __builtin_amdgcn_mfma_f32_16x16x32_f16(wa[2][1], sb1, acc, 0, 0, 0);
            hw2 = (_Float16)lstm_cell(acc, c2);
        }
        if (doL1) {
            if (w < 12) {                          // wave-uniform: 12 waves take this
                ((_Float16*)h1n)[wOff] = hw1;
            } else {                               // wave 12: units 48..51
                if (qq < 2)       ((_Float16*)h1n)[wOff] = hw1;           // 48,49
                else if (qq == 2) ((_Float16*)h1n)[wOff] =
                                      (_Float16)xrow[p + 1];              // x lane
                /* qq == 3: 1.0 lane, pre-written, never touched */
            }
        }
        if (doL2) ((_Float16*)h2n)[wOff] = hw2;
        __syncthreads();
    };

    // phase p reads buf[p&1], writes buf[1-(p&1)]
    phase(h1f[0], h2f[0], h1f[1], h2f[1], 0, true, false);      // L1[0]
#pragma unroll 1
    for (int p = 1; p <= 509; p += 2) {
        phase(h1f[1], h2f[1], h1f[0], h2f[0], p,     true, true);
        phase(h1f[0], h2f[0], h1f[1], h2f[1], p + 1, true, true);
    }
    phase(h1f[1], h2f[1], h1f[0], h2f[0], 511, true,  true);
    phase(h1f[0], h2f[0], h1f[1], h2f[1], 512, false, true);    // L2[511]
    // h2[511] now lives in h2f[1]

    // ============ FC head: out[b] = h2[T-1] . fc_w + fc_b ============
    if (tid < NB) {
        const int m = tid;
        const _Float16* h2e = (const _Float16*)h2f[1];
        float s = fc_b[0];
        for (int j = 0; j < HID; ++j) {
            const int chunk = (((j >> 5) * 4) + ((j >> 3) & 3)) * 16 + m;
            s += fc_w[j] * (float)h2e[chunk * 8 + (j & 7)];
        }
        out[b0 + m] = s;
    }
}

extern "C" void kernel_launch(void* const* d_in, const int* in_sizes, int n_in,
                              void* d_out, int out_size, void* d_ws, size_t ws_size,
                              hipStream_t stream) {
    const float* x     = (const float*)d_in[0];
    const float* w_ih0 = (const float*)d_in[1];
    const float* w_hh0 = (const float*)d_in[2];
    const float* b_ih0 = (const float*)d_in[3];
    const float* b_hh0 = (const float*)d_in[4];
    const float* w_ih1 = (const float*)d_in[5];
    const float* w_hh1 = (const float*)d_in[6];
    const float* b_ih1 = (const float*)d_in[7];
    const float* b_hh1 = (const float*)d_in[8];
    const float* fc_w  = (const float*)d_in[9];
    const float* fc_b  = (const float*)d_in[10];
    float* out = (float*)d_out;

    const int B = in_sizes[0] / SEQ;  // 4096

    lstm2_fc_v9<<<B / NB, NTHREADS, 0, stream>>>(
        x, w_ih0, w_hh0, b_ih0, b_hh0, w_ih1, w_hh1, b_ih1, b_hh1, fc_w, fc_b, out);
}